// Round 7
// baseline (145.854 us; speedup 1.0000x reference)
//
#include <hip/hip_runtime.h>
#include <hip/hip_bf16.h>

constexpr int L_LEN = 4096;
constexpr int CH = 8;          // channels
constexpr int S_SAMPLES = 256; // continuous start samples
constexpr int K_SAMP = 32;     // shapelet samples
constexpr int NSHAPE = 16;
constexpr int NB = 32;         // batch
constexpr int NPB = 2;                  // p values per block
constexpr int NPBLK = S_SAMPLES / NPB;  // 128 p-blocks
constexpr int THREADS = 256;            // b(32) x quarter(4) x pl(2)
constexpr int NBLOCKS = NPBLK * NSHAPE; // 2048

typedef float v2f __attribute__((ext_vector_type(2)));

__device__ __forceinline__ v2f bfpair(unsigned u) {
    v2f r;
    r.x = __uint_as_float(u << 16);
    r.y = __uint_as_float(u & 0xffff0000u);
    return r;
}
__device__ __forceinline__ unsigned short f2bf(float f) {
    unsigned u = __float_as_uint(f);
    u = (u + 0x7fffu + ((u >> 16) & 1u)) >> 16;   // RNE (inputs finite)
    return (unsigned short)u;
}

// path (B,L,C) f32 -> ws (L,B,C) bf16; also inits ws_min + ticket (stream-ordered)
__global__ __launch_bounds__(256) void transpose_kernel(const float4* __restrict__ src,
                                                        uint4* __restrict__ dst,
                                                        unsigned* __restrict__ ws_min,
                                                        unsigned* __restrict__ ticket) {
    const int t = blockIdx.x * 256 + threadIdx.x;  // 131072 = L*B
    if (t < NSHAPE * NB) ws_min[t] = 0x7f7f7f7fu;  // ~3.39e38
    if (t == NSHAPE * NB) *ticket = 0u;
    const int b = t & (NB - 1);
    const int l = t >> 5;
    const float4 f0 = src[(b * L_LEN + l) * 2 + 0];
    const float4 f1 = src[(b * L_LEN + l) * 2 + 1];
    uint4 o;
    o.x = (unsigned)f2bf(f0.x) | ((unsigned)f2bf(f0.y) << 16);
    o.y = (unsigned)f2bf(f0.z) | ((unsigned)f2bf(f0.w) << 16);
    o.z = (unsigned)f2bf(f1.x) | ((unsigned)f2bf(f1.y) << 16);
    o.w = (unsigned)f2bf(f1.z) | ((unsigned)f2bf(f1.w) << 16);
    dst[t] = o;   // 16B per (l,b), coalesced
}

// tid bits: [0:4]=b, [5]=q_lo, [6]=q_hi, [7]=pl  (quarter = bits 5:6)
__global__ __launch_bounds__(THREADS) void shapelet_min_kernel(
    const uint4* __restrict__ wst,       // (L, B, C/2) bf16-packed path
    const float* __restrict__ lengths,   // (NSHAPE)
    const float* __restrict__ shapelets, // (NSHAPE, K, C)
    unsigned* __restrict__ ws_min,       // (NSHAPE, NB) float-as-uint
    unsigned* __restrict__ ticket,
    float* __restrict__ out)             // (NB, NSHAPE)
{
    __shared__ v2f sh2[K_SAMP][5];       // 4 pairs + pad (row 40B)
    __shared__ float sred[NPB][2][NB];   // [pl][q_hi][b]
    __shared__ unsigned lastFlag;

    const int s       = blockIdx.y;
    const int tid     = threadIdx.x;
    const int b       = tid & (NB - 1);
    const int quarter = (tid >> 5) & 3;
    const int q_hi    = (tid >> 6) & 1;
    const int pl      = tid >> 7;                  // 0..1
    const int p       = blockIdx.x * NPB + pl;     // 0..255

    ((float*)&sh2[tid >> 3][0])[tid & 7] = shapelets[s * K_SAMP * CH + tid];
    __syncthreads();

    const float len   = fminf(fmaxf(lengths[s], 0.01f), 512.0f);
    const float start = ((float)p / (float)(S_SAMPLES - 1)) * ((float)(L_LEN - 1) - len);
    const float step  = len * (1.0f / (float)(K_SAMP - 1));
    const int   k0    = quarter * (K_SAMP / 4);    // 0, 8, 16, 24

    v2f dprev[4];
    #pragma unroll
    for (int j = 0; j < 4; ++j) { dprev[j].x = 0.f; dprev[j].y = 0.f; }
    float sqprev = 0.f, segsum = 0.f;

    #pragma unroll
    for (int i = 0; i <= K_SAMP / 4; ++i) {
        const int k  = k0 + i;
        const int kk = min(k, K_SAMP - 1);
        const float q = start + (float)kk * step;  // q >= 0 so (int)q == floor
        const int idx = min((int)q, L_LEN - 2);
        const float r = q - (float)idx;
        const int base = idx * NB + b;
        const uint4 A  = wst[base];
        const uint4 Cu = wst[base + NB];
        const unsigned au[4] = {A.x, A.y, A.z, A.w};
        const unsigned cu[4] = {Cu.x, Cu.y, Cu.z, Cu.w};

        v2f rr; rr.x = r; rr.y = r;
        v2f sqv;  sqv.x = 0.f;  sqv.y = 0.f;
        v2f dotv; dotv.x = 0.f; dotv.y = 0.f;
        v2f dnew[4];
        #pragma unroll
        for (int j = 0; j < 4; ++j) {
            const v2f P = bfpair(au[j]);
            const v2f N = bfpair(cu[j]);
            const v2f samp = P + rr * (N - P);
            const v2f d = samp - sh2[kk][j];
            sqv  += d * d;
            dotv += dprev[j] * d;
            dnew[j] = d;
        }
        const float sq = sqv.x + sqv.y;
        if (i > 0) {
            const float dot = dotv.x + dotv.y;
            const float w = (k <= K_SAMP - 1) ? 1.0f : 0.0f;
            segsum += w * (sqprev + dot + sq);
        }
        sqprev = sq;
        #pragma unroll
        for (int j = 0; j < 4; ++j) dprev[j] = dnew[j];
    }

    // combine quarter pairs (lane bit 5, same wave)
    segsum += __shfl_xor(segsum, 32);
    if ((tid & 32) == 0) sred[pl][q_hi][b] = segsum;
    __syncthreads();

    if (tid < 64) {
        const int bb  = tid & (NB - 1);
        const int plx = tid >> 5;
        const float tot = sred[plx][0][bb] + sred[plx][1][bb];
        float integral = len * (1.0f / (3.0f * (float)(K_SAMP - 1))) * tot;
        integral = fmaxf(integral, 0.0f);
        // min over the block's two p values (lane bit 5)
        const float m = fminf(integral, __shfl_xor(integral, 32));
        if (tid < NB)
            atomicMin(ws_min + s * NB + bb, __float_as_uint(m));
    }

    // last-block finalize (deterministic: min is order-independent)
    __threadfence();
    if (tid == 0) {
        const unsigned t = atomicAdd(ticket, 1u);
        lastFlag = (t == NBLOCKS - 1) ? 1u : 0u;
    }
    __syncthreads();
    if (lastFlag) {
        __threadfence();
        for (int i = tid; i < NSHAPE * NB; i += THREADS) {
            const int ss = i >> 5;
            const int bb = i & (NB - 1);
            const float v = __uint_as_float(ws_min[i]);
            out[bb * NSHAPE + ss] = sqrtf(fmaxf(v, 1e-12f));
        }
    }
}

extern "C" void kernel_launch(void* const* d_in, const int* in_sizes, int n_in,
                              void* d_out, int out_size, void* d_ws, size_t ws_size,
                              hipStream_t stream) {
    // inputs: times (L), path (B,L,C), lengths (NSHAPE), shapelets (NSHAPE,K,C)
    const float* path      = (const float*)d_in[1];
    const float* lengths   = (const float*)d_in[2];
    const float* shapelets = (const float*)d_in[3];
    float* out = (float*)d_out;

    unsigned* ws_min = (unsigned*)d_ws;                       // 512 uints
    unsigned* ticket = ws_min + NSHAPE * NB;                  // 1 uint
    uint4*    wst    = (uint4*)((char*)d_ws + 4096);          // 2 MB, aligned

    transpose_kernel<<<L_LEN * NB / 256, 256, 0, stream>>>(
        (const float4*)path, wst, ws_min, ticket);
    dim3 grid(NPBLK, NSHAPE);
    shapelet_min_kernel<<<grid, THREADS, 0, stream>>>(
        wst, lengths, shapelets, ws_min, ticket, out);
}

// Round 8
// 22.173 us; speedup vs baseline: 6.5780x; 6.5780x over previous
//
#include <hip/hip_runtime.h>
#include <hip/hip_bf16.h>

constexpr int L_LEN = 4096;
constexpr int CH = 8;          // channels
constexpr int S_SAMPLES = 256; // continuous start samples
constexpr int K_SAMP = 32;     // shapelet samples
constexpr int NSHAPE = 16;
constexpr int NB = 32;         // batch
constexpr int NPB = 2;                  // p values per block
constexpr int NPBLK = S_SAMPLES / NPB;  // 128 p-blocks
constexpr int THREADS = 256;            // b(32) x quarter(4) x pl(2)

typedef float v2f __attribute__((ext_vector_type(2)));

__device__ __forceinline__ v2f bfpair(unsigned u) {
    v2f r;
    r.x = __uint_as_float(u << 16);
    r.y = __uint_as_float(u & 0xffff0000u);
    return r;
}
__device__ __forceinline__ unsigned short f2bf(float f) {
    unsigned u = __float_as_uint(f);
    u = (u + 0x7fffu + ((u >> 16) & 1u)) >> 16;   // RNE (inputs finite)
    return (unsigned short)u;
}

// path (B,L,C) f32 -> ws (L,B,C) bf16-packed; one thread per (l,b) row of 8 ch
__global__ __launch_bounds__(256) void transpose_kernel(const float4* __restrict__ src,
                                                        uint4* __restrict__ dst) {
    const int t = blockIdx.x * 256 + threadIdx.x;  // 131072 = L*B
    const int b = t & (NB - 1);
    const int l = t >> 5;
    const float4 f0 = src[(b * L_LEN + l) * 2 + 0];
    const float4 f1 = src[(b * L_LEN + l) * 2 + 1];
    uint4 o;
    o.x = (unsigned)f2bf(f0.x) | ((unsigned)f2bf(f0.y) << 16);
    o.y = (unsigned)f2bf(f0.z) | ((unsigned)f2bf(f0.w) << 16);
    o.z = (unsigned)f2bf(f1.x) | ((unsigned)f2bf(f1.y) << 16);
    o.w = (unsigned)f2bf(f1.z) | ((unsigned)f2bf(f1.w) << 16);
    dst[t] = o;   // 16B per (l,b), coalesced
}

// tid bits: [0:4]=b, [5]=q_lo, [6]=q_hi, [7]=pl  (quarter = bits 5:6)
__global__ __launch_bounds__(THREADS) void shapelet_min_kernel(
    const uint4* __restrict__ wst,       // (L, B, C/2) bf16-packed path
    const float* __restrict__ lengths,   // (NSHAPE)
    const float* __restrict__ shapelets, // (NSHAPE, K, C)
    float* __restrict__ partial)         // (NSHAPE, NPBLK, NB)
{
    __shared__ v2f sh2[K_SAMP][5];       // 4 pairs + 8B pad (row 40B, conflict-free)
    __shared__ float sred[NPB][2][NB];   // [pl][q_hi][b]

    const int s       = blockIdx.y;
    const int tid     = threadIdx.x;
    const int b       = tid & (NB - 1);
    const int q_hi    = (tid >> 6) & 1;
    const int pl      = tid >> 7;                  // 0..1
    const int p       = blockIdx.x * NPB + pl;     // 0..255

    ((float*)&sh2[tid >> 3][0])[tid & 7] = shapelets[s * K_SAMP * CH + tid];
    __syncthreads();

    const float len   = fminf(fmaxf(lengths[s], 0.01f), 512.0f);
    const float start = ((float)p / (float)(S_SAMPLES - 1)) * ((float)(L_LEN - 1) - len);
    const float step  = len * (1.0f / (float)(K_SAMP - 1));
    const int   k0    = ((tid >> 5) & 3) * (K_SAMP / 4);    // 0, 8, 16, 24

    v2f dprev[4];
    #pragma unroll
    for (int j = 0; j < 4; ++j) { dprev[j].x = 0.f; dprev[j].y = 0.f; }
    float sqprev = 0.f, segsum = 0.f;

    #pragma unroll
    for (int i = 0; i <= K_SAMP / 4; ++i) {
        const int k  = k0 + i;
        const int kk = min(k, K_SAMP - 1);
        const float q = start + (float)kk * step;  // q >= 0 so (int)q == floor
        const int idx = min((int)q, L_LEN - 2);
        const float r = q - (float)idx;
        const int base = idx * NB + b;
        const uint4 A  = wst[base];
        const uint4 Cu = wst[base + NB];
        const unsigned au[4] = {A.x, A.y, A.z, A.w};
        const unsigned cu[4] = {Cu.x, Cu.y, Cu.z, Cu.w};

        v2f rr; rr.x = r; rr.y = r;
        v2f sqv;  sqv.x = 0.f;  sqv.y = 0.f;
        v2f dotv; dotv.x = 0.f; dotv.y = 0.f;
        v2f dnew[4];
        #pragma unroll
        for (int j = 0; j < 4; ++j) {
            const v2f P = bfpair(au[j]);
            const v2f N = bfpair(cu[j]);
            const v2f samp = P + rr * (N - P);
            const v2f d = samp - sh2[kk][j];
            sqv  += d * d;
            dotv += dprev[j] * d;
            dnew[j] = d;
        }
        const float sq = sqv.x + sqv.y;
        if (i > 0) {
            const float dot = dotv.x + dotv.y;
            const float w = (k <= K_SAMP - 1) ? 1.0f : 0.0f;
            segsum += w * (sqprev + dot + sq);
        }
        sqprev = sq;
        #pragma unroll
        for (int j = 0; j < 4; ++j) dprev[j] = dnew[j];
    }

    // combine quarter pairs (lane bit 5, same wave)
    segsum += __shfl_xor(segsum, 32);
    if ((tid & 32) == 0) sred[pl][q_hi][b] = segsum;
    __syncthreads();

    if (tid < 64) {
        const int bb  = tid & (NB - 1);
        const int plx = tid >> 5;
        const float tot = sred[plx][0][bb] + sred[plx][1][bb];
        float integral = len * (1.0f / (3.0f * (float)(K_SAMP - 1))) * tot;
        integral = fmaxf(integral, 0.0f);
        // min over the block's two p values (lane bit 5)
        const float m = fminf(integral, __shfl_xor(integral, 32));
        if (tid < NB)
            partial[(s * NPBLK + blockIdx.x) * NB + bb] = m;
    }
}

// one block per shapelet; 256 threads = b(32) x chunk(8)
__global__ __launch_bounds__(256) void shapelet_finalize_kernel(
    const float* __restrict__ partial, float* __restrict__ out)
{
    __shared__ float fred[8][NB];
    const int s     = blockIdx.x;
    const int tid   = threadIdx.x;
    const int b     = tid & (NB - 1);
    const int chunk = tid >> 5;                   // 0..7
    float m = 3.4e38f;
    #pragma unroll
    for (int j = 0; j < NPBLK / 8; ++j) {
        const int pb = chunk * (NPBLK / 8) + j;
        m = fminf(m, partial[(s * NPBLK + pb) * NB + b]);
    }
    fred[chunk][b] = m;
    __syncthreads();
    if (tid < NB) {
        float mm = fred[0][tid];
        #pragma unroll
        for (int j = 1; j < 8; ++j) mm = fminf(mm, fred[j][tid]);
        out[tid * NSHAPE + s] = sqrtf(fmaxf(mm, 1e-12f));
    }
}

extern "C" void kernel_launch(void* const* d_in, const int* in_sizes, int n_in,
                              void* d_out, int out_size, void* d_ws, size_t ws_size,
                              hipStream_t stream) {
    // inputs: times (L), path (B,L,C), lengths (NSHAPE), shapelets (NSHAPE,K,C)
    const float* path      = (const float*)d_in[1];
    const float* lengths   = (const float*)d_in[2];
    const float* shapelets = (const float*)d_in[3];
    float* out = (float*)d_out;

    uint4* wst     = (uint4*)d_ws;                                        // 2 MB
    float* partial = (float*)((char*)d_ws + (size_t)L_LEN * NB * 16);     // 256 KB

    transpose_kernel<<<L_LEN * NB / 256, 256, 0, stream>>>(
        (const float4*)path, wst);
    dim3 grid(NPBLK, NSHAPE);
    shapelet_min_kernel<<<grid, THREADS, 0, stream>>>(wst, lengths, shapelets, partial);
    shapelet_finalize_kernel<<<NSHAPE, 256, 0, stream>>>(partial, out);
}

// Round 9
// 21.842 us; speedup vs baseline: 6.6775x; 1.0151x over previous
//
#include <hip/hip_runtime.h>
#include <hip/hip_bf16.h>

constexpr int L_LEN = 4096;
constexpr int CH = 8;          // channels
constexpr int S_SAMPLES = 256; // continuous start samples
constexpr int K_SAMP = 32;     // shapelet samples
constexpr int NSHAPE = 16;
constexpr int NB = 32;         // batch
constexpr int NPB = 4;                  // p values per block
constexpr int NPBLK = S_SAMPLES / NPB;  // 64 p-blocks
constexpr int THREADS = 512;            // b(32) x quarter(4) x pl(4)

typedef float v2f __attribute__((ext_vector_type(2)));

__device__ __forceinline__ v2f bfpair(unsigned u) {
    v2f r;
    r.x = __uint_as_float(u << 16);
    r.y = __uint_as_float(u & 0xffff0000u);
    return r;
}
__device__ __forceinline__ unsigned short f2bf(float f) {
    unsigned u = __float_as_uint(f);
    u = (u + 0x7fffu + ((u >> 16) & 1u)) >> 16;   // RNE (inputs finite)
    return (unsigned short)u;
}

// path (B,L,C) f32 -> ws (L,B,C) bf16-packed.
// lanes -> consecutive l: reads contiguous (100% line use, 4MB total);
// writes are 16B @ 512B stride into the L2-resident 2MB buffer (cheap).
__global__ __launch_bounds__(256) void transpose_kernel(const float4* __restrict__ src,
                                                        uint4* __restrict__ dst) {
    const int t = blockIdx.x * 256 + threadIdx.x;  // 131072 = L*B
    const int l = t & (L_LEN - 1);
    const int b = t >> 12;
    const float4 f0 = src[(b * L_LEN + l) * 2 + 0];
    const float4 f1 = src[(b * L_LEN + l) * 2 + 1];
    uint4 o;
    o.x = (unsigned)f2bf(f0.x) | ((unsigned)f2bf(f0.y) << 16);
    o.y = (unsigned)f2bf(f0.z) | ((unsigned)f2bf(f0.w) << 16);
    o.z = (unsigned)f2bf(f1.x) | ((unsigned)f2bf(f1.y) << 16);
    o.w = (unsigned)f2bf(f1.z) | ((unsigned)f2bf(f1.w) << 16);
    dst[l * NB + b] = o;
}

// tid bits: [0:4]=b, [5]=q_lo, [6]=q_hi, [7:8]=pl  (quarter = bits 5:6)
__global__ __launch_bounds__(THREADS) void shapelet_min_kernel(
    const uint4* __restrict__ wst,       // (L, B, C/2) bf16-packed path
    const float* __restrict__ lengths,   // (NSHAPE)
    const float* __restrict__ shapelets, // (NSHAPE, K, C)
    float* __restrict__ partial)         // (NSHAPE, NPBLK, NB)
{
    __shared__ v2f sh2[K_SAMP][5];       // 4 pairs + 8B pad (row 40B, conflict-free)
    __shared__ float sred[NPB][2][NB];   // [pl][q_hi][b]
    __shared__ float cand[2][NB];

    const int s       = blockIdx.y;
    const int tid     = threadIdx.x;
    const int b       = tid & (NB - 1);
    const int q_hi    = (tid >> 6) & 1;
    const int pl      = tid >> 7;                  // 0..3
    const int p       = blockIdx.x * NPB + pl;     // 0..255

    if (tid < K_SAMP * CH)
        ((float*)&sh2[tid >> 3][0])[tid & 7] = shapelets[s * K_SAMP * CH + tid];
    __syncthreads();

    const float len   = fminf(fmaxf(lengths[s], 0.01f), 512.0f);
    const float start = ((float)p / (float)(S_SAMPLES - 1)) * ((float)(L_LEN - 1) - len);
    const float step  = len * (1.0f / (float)(K_SAMP - 1));
    const int   k0    = ((tid >> 5) & 3) * (K_SAMP / 4);    // 0, 8, 16, 24

    v2f dprev[4];
    #pragma unroll
    for (int j = 0; j < 4; ++j) { dprev[j].x = 0.f; dprev[j].y = 0.f; }
    float sqprev = 0.f, segsum = 0.f;

    #pragma unroll
    for (int i = 0; i <= K_SAMP / 4; ++i) {
        const int k  = k0 + i;
        const int kk = min(k, K_SAMP - 1);
        const float q = start + (float)kk * step;  // q >= 0 so (int)q == floor
        const int idx = min((int)q, L_LEN - 2);
        const float r = q - (float)idx;
        const int base = idx * NB + b;
        const uint4 A  = wst[base];
        const uint4 Cu = wst[base + NB];
        const unsigned au[4] = {A.x, A.y, A.z, A.w};
        const unsigned cu[4] = {Cu.x, Cu.y, Cu.z, Cu.w};

        v2f rr; rr.x = r; rr.y = r;
        v2f sqv;  sqv.x = 0.f;  sqv.y = 0.f;
        v2f dotv; dotv.x = 0.f; dotv.y = 0.f;
        v2f dnew[4];
        #pragma unroll
        for (int j = 0; j < 4; ++j) {
            const v2f P = bfpair(au[j]);
            const v2f N = bfpair(cu[j]);
            const v2f samp = P + rr * (N - P);
            const v2f d = samp - sh2[kk][j];
            sqv  += d * d;
            dotv += dprev[j] * d;
            dnew[j] = d;
        }
        const float sq = sqv.x + sqv.y;
        if (i > 0) {
            const float dot = dotv.x + dotv.y;
            const float w = (k <= K_SAMP - 1) ? 1.0f : 0.0f;
            segsum += w * (sqprev + dot + sq);
        }
        sqprev = sq;
        #pragma unroll
        for (int j = 0; j < 4; ++j) dprev[j] = dnew[j];
    }

    // combine quarter pairs (lane bit 5, same wave)
    segsum += __shfl_xor(segsum, 32);
    if ((tid & 32) == 0) sred[pl][q_hi][b] = segsum;
    __syncthreads();

    // integral per (pl, b), then min over the block's 4 p values
    if (tid < 128) {
        const int bb  = tid & (NB - 1);
        const int plx = tid >> 5;                  // 0..3
        const float tot = sred[plx][0][bb] + sred[plx][1][bb];
        float integral = len * (1.0f / (3.0f * (float)(K_SAMP - 1))) * tot;
        integral = fmaxf(integral, 0.0f);
        const float m1 = fminf(integral, __shfl_xor(integral, 32)); // pl pairs
        if ((tid & 32) == 0) cand[tid >> 6][bb] = m1;
    }
    __syncthreads();
    if (tid < NB)
        partial[(s * NPBLK + blockIdx.x) * NB + tid] = fminf(cand[0][tid], cand[1][tid]);
}

// one block per shapelet; 256 threads = b(32) x chunk(8)
__global__ __launch_bounds__(256) void shapelet_finalize_kernel(
    const float* __restrict__ partial, float* __restrict__ out)
{
    __shared__ float fred[8][NB];
    const int s     = blockIdx.x;
    const int tid   = threadIdx.x;
    const int b     = tid & (NB - 1);
    const int chunk = tid >> 5;                   // 0..7
    float m = 3.4e38f;
    #pragma unroll
    for (int j = 0; j < NPBLK / 8; ++j) {
        const int pb = chunk * (NPBLK / 8) + j;
        m = fminf(m, partial[(s * NPBLK + pb) * NB + b]);
    }
    fred[chunk][b] = m;
    __syncthreads();
    if (tid < NB) {
        float mm = fred[0][tid];
        #pragma unroll
        for (int j = 1; j < 8; ++j) mm = fminf(mm, fred[j][tid]);
        out[tid * NSHAPE + s] = sqrtf(fmaxf(mm, 1e-12f));
    }
}

extern "C" void kernel_launch(void* const* d_in, const int* in_sizes, int n_in,
                              void* d_out, int out_size, void* d_ws, size_t ws_size,
                              hipStream_t stream) {
    // inputs: times (L), path (B,L,C), lengths (NSHAPE), shapelets (NSHAPE,K,C)
    const float* path      = (const float*)d_in[1];
    const float* lengths   = (const float*)d_in[2];
    const float* shapelets = (const float*)d_in[3];
    float* out = (float*)d_out;

    uint4* wst     = (uint4*)d_ws;                                        // 2 MB
    float* partial = (float*)((char*)d_ws + (size_t)L_LEN * NB * 16);     // 16 KB

    transpose_kernel<<<L_LEN * NB / 256, 256, 0, stream>>>(
        (const float4*)path, wst);
    dim3 grid(NPBLK, NSHAPE);
    shapelet_min_kernel<<<grid, THREADS, 0, stream>>>(wst, lengths, shapelets, partial);
    shapelet_finalize_kernel<<<NSHAPE, 256, 0, stream>>>(partial, out);
}